// Round 2
// baseline (1399.974 us; speedup 1.0000x reference)
//
#include <hip/hip_runtime.h>
#include <cstddef>

#define NB 65536
#define SL 5

__device__ __forceinline__ float sigm(float x)   { return 1.0f / (1.0f + __expf(-x)); }
__device__ __forceinline__ float tanh_f(float x) { return 2.0f / (1.0f + __expf(-2.0f * x)) - 1.0f; }

// ---------------------------------------------------------------------------
// Phase A: 2x (message + attention-weighted sum + GRU), thread per (b,s).
// Unit-outer / node-inner with merged gates: each weight row is loaded once
// and consumed 4x immediately (no cross-node hoisting blowup); r is never
// stored. Writes x transposed as xt[s][feat][b] for coalesced phase-B reads.
// ---------------------------------------------------------------------------
__global__ __launch_bounds__(256) void msg_pass_kernel(
    const float* __restrict__ nf, const float* __restrict__ pos,
    const float* __restrict__ att,
    const float* __restrict__ msg_w, const float* __restrict__ msg_b,
    const float* __restrict__ gw_ih, const float* __restrict__ gw_hh,
    const float* __restrict__ gb_ih, const float* __restrict__ gb_hh,
    float* __restrict__ xt)
{
  const int t = blockIdx.x * 256 + threadIdx.x;   // t in [0, NB*SL)
  const int s = t / NB;
  const int b = t - s * NB;
  const size_t base = ((size_t)b * SL + s) * 24;

  // h init = concat(nodes_feature, pos); transient float4 loads
  float h[4][12];
  {
    float4 tn[6], tp[6];
    const float4* n4 = (const float4*)(nf  + base);
    const float4* p4 = (const float4*)(pos + base);
#pragma unroll
    for (int q = 0; q < 6; q++) { tn[q] = n4[q]; tp[q] = p4[q]; }
    const float* fn = (const float*)tn;
    const float* fp = (const float*)tp;
#pragma unroll
    for (int k = 0; k < 4; k++) {
#pragma unroll
      for (int d = 0; d < 6; d++) { h[k][d] = fn[k*6+d]; h[k][6+d] = fp[k*6+d]; }
    }
  }
  float ta[16];
  {
    const float4* a4 = (const float4*)(att + (size_t)(b * SL + s) * 16);
#pragma unroll
    for (int q = 0; q < 4; q++) {
      float4 v = a4[q];
      ta[q*4+0] = v.x; ta[q*4+1] = v.y; ta[q*4+2] = v.z; ta[q*4+3] = v.w;
    }
  }

#pragma unroll 1
  for (int pass = 0; pass < 2; ++pass) {
    // m_all = h @ msg_w.T + msg_b   (unit-outer, node-inner)
    float ma[4][12];
#pragma unroll
    for (int j = 0; j < 12; j++) {
#pragma unroll
      for (int w = 0; w < 4; w++) {
        float acc = msg_b[j];
#pragma unroll
        for (int i = 0; i < 12; i++) acc = __builtin_fmaf(msg_w[j*12+i], h[w][i], acc);
        ma[w][j] = acc;
      }
    }
    // m_v[n][d] = sum_w att[n][w] * m_all[w][d]
    float mv[4][12];
#pragma unroll
    for (int n = 0; n < 4; n++) {
#pragma unroll
      for (int d = 0; d < 12; d++) {
        mv[n][d] = ta[n*4+0]*ma[0][d] + ta[n*4+1]*ma[1][d]
                 + ta[n*4+2]*ma[2][d] + ta[n*4+3]*ma[3][d];
      }
    }
    // GRU: all three gates merged per unit j; r,z,g are scalars per (j,n)
    float hn[4][12];
#pragma unroll
    for (int j = 0; j < 12; j++) {
#pragma unroll
      for (int n = 0; n < 4; n++) {
        float ar  = gb_ih[j]      + gb_hh[j];
        float az  = gb_ih[12+j]   + gb_hh[12+j];
        float ani = gb_ih[24+j];
        float anh = gb_hh[24+j];
#pragma unroll
        for (int i = 0; i < 12; i++) {
          const float mvi = mv[n][i];
          const float hi  = h[n][i];
          ar  = __builtin_fmaf(gw_ih[j*12+i],        mvi, ar);
          ar  = __builtin_fmaf(gw_hh[j*12+i],        hi,  ar);
          az  = __builtin_fmaf(gw_ih[(12+j)*12+i],   mvi, az);
          az  = __builtin_fmaf(gw_hh[(12+j)*12+i],   hi,  az);
          ani = __builtin_fmaf(gw_ih[(24+j)*12+i],   mvi, ani);
          anh = __builtin_fmaf(gw_hh[(24+j)*12+i],   hi,  anh);
        }
        const float r = sigm(ar);
        const float z = sigm(az);
        const float g = tanh_f(ani + r * anh);
        hn[n][j] = (1.0f - z) * g + z * h[n][j];
      }
    }
#pragma unroll
    for (int n = 0; n < 4; n++) {
#pragma unroll
      for (int j = 0; j < 12; j++) h[n][j] = hn[n][j];
    }
  }

  // x[b,s,d*4+k] = h[k][d]; store transposed xt[(s*48 + d*4 + k)*NB + b]
#pragma unroll
  for (int d = 0; d < 12; d++) {
#pragma unroll
    for (int k = 0; k < 4; k++) {
      xt[(size_t)(s * 48 + d * 4 + k) * NB + b] = h[k][d];
    }
  }
}

// ---------------------------------------------------------------------------
// Phase B+C: bidirectional LSTM (5 steps) + MLP head.
// Thread = (batch, dir); dir = wave index (wave-uniform => weights via s_load).
// c / h_next live in LDS (runtime-j indexing is fine for memory; only register
// arrays need static indices). Lane-consecutive LDS columns => conflict-free.
// No scratch, no HBM round-trip for recurrent state.
// ---------------------------------------------------------------------------
__global__ __launch_bounds__(128) void lstm_head_kernel(
    const float* __restrict__ xt,
    const float* __restrict__ wi_fw, const float* __restrict__ wh_fw,
    const float* __restrict__ bi_fw, const float* __restrict__ bh_fw,
    const float* __restrict__ wi_bw, const float* __restrict__ wh_bw,
    const float* __restrict__ bi_bw, const float* __restrict__ bh_bw,
    const float* __restrict__ e1w, const float* __restrict__ e1b,
    const float* __restrict__ e2w, const float* __restrict__ e2b,
    const float* __restrict__ e3w, const float* __restrict__ e3b,
    float* __restrict__ out)
{
  __shared__ float c_lds[48][128];
  __shared__ float hn_lds[48][128];

  const int tid  = threadIdx.x;
  const int lane = tid & 63;
  const int dir  = __builtin_amdgcn_readfirstlane(tid >> 6);  // wave-uniform
  const int b    = blockIdx.x * 64 + lane;

  const float* __restrict__ wi = dir ? wi_bw : wi_fw;
  const float* __restrict__ wh = dir ? wh_bw : wh_fw;
  const float* __restrict__ bi = dir ? bi_bw : bi_fw;
  const float* __restrict__ bh = dir ? bh_bw : bh_fw;

  float hreg[48];               // registers (static indexing only)
#pragma unroll
  for (int k = 0; k < 48; k++) hreg[k] = 0.0f;
#pragma unroll
  for (int j = 0; j < 48; j++) c_lds[j][tid] = 0.0f;  // own column, no barrier

#pragma unroll 1
  for (int st = 0; st < 5; ++st) {
    const int s = dir ? (4 - st) : st;
    float xv[48];
#pragma unroll
    for (int j = 0; j < 48; j++) xv[j] = xt[(size_t)(s * 48 + j) * NB + b];

#pragma unroll 2
    for (int j = 0; j < 48; j++) {   // unit loop — gates i,f,g,o
      float gi = bi[j]       + bh[j];
      float gf = bi[48 + j]  + bh[48 + j];
      float gg = bi[96 + j]  + bh[96 + j];
      float go = bi[144 + j] + bh[144 + j];
      const float* __restrict__ wij = wi + j * 48;
      const float* __restrict__ whj = wh + j * 48;
#pragma unroll
      for (int k = 0; k < 48; k++) {
        const float xk = xv[k];
        const float hk = hreg[k];
        gi = __builtin_fmaf(wij[k],        xk, gi);
        gi = __builtin_fmaf(whj[k],        hk, gi);
        gf = __builtin_fmaf(wij[2304 + k], xk, gf);
        gf = __builtin_fmaf(whj[2304 + k], hk, gf);
        gg = __builtin_fmaf(wij[4608 + k], xk, gg);
        gg = __builtin_fmaf(whj[4608 + k], hk, gg);
        go = __builtin_fmaf(wij[6912 + k], xk, go);
        go = __builtin_fmaf(whj[6912 + k], hk, go);
      }
      const float cold = c_lds[j][tid];
      const float c = sigm(gf) * cold + sigm(gi) * tanh_f(gg);
      c_lds[j][tid]  = c;
      hn_lds[j][tid] = sigm(go) * tanh_f(c);
    }
#pragma unroll
    for (int k = 0; k < 48; k++) hreg[k] = hn_lds[k][tid];
  }

  __syncthreads();              // publish hn_lds columns across waves
  if (dir != 0) return;

  float hcat[96];
#pragma unroll
  for (int k = 0; k < 48; k++) { hcat[k] = hreg[k]; hcat[48 + k] = hn_lds[k][64 + lane]; }

  // MLP head: 96 -> 48 relu -> 36 relu -> 6
  float e1[48];
#pragma unroll
  for (int r = 0; r < 48; r++) {
    float a = e1b[r];
#pragma unroll
    for (int k = 0; k < 96; k++) a = __builtin_fmaf(e1w[r * 96 + k], hcat[k], a);
    e1[r] = a > 0.0f ? a : 0.0f;
  }
  float e2[36];
#pragma unroll
  for (int r = 0; r < 36; r++) {
    float a = e2b[r];
#pragma unroll
    for (int k = 0; k < 48; k++) a = __builtin_fmaf(e2w[r * 48 + k], e1[k], a);
    e2[r] = a > 0.0f ? a : 0.0f;
  }
#pragma unroll
  for (int r = 0; r < 6; r++) {
    float a = e3b[r];
#pragma unroll
    for (int k = 0; k < 36; k++) a = __builtin_fmaf(e3w[r * 36 + k], e2[k], a);
    out[(size_t)b * 6 + r] = a;
  }
}

extern "C" void kernel_launch(void* const* d_in, const int* in_sizes, int n_in,
                              void* d_out, int out_size, void* d_ws, size_t ws_size,
                              hipStream_t stream)
{
  const float* nf    = (const float*)d_in[0];
  const float* pos   = (const float*)d_in[1];
  const float* att   = (const float*)d_in[2];
  const float* msg_w = (const float*)d_in[3];
  const float* msg_b = (const float*)d_in[4];
  const float* gw_ih = (const float*)d_in[5];
  const float* gw_hh = (const float*)d_in[6];
  const float* gb_ih = (const float*)d_in[7];
  const float* gb_hh = (const float*)d_in[8];
  const float* wi_fw = (const float*)d_in[9];
  const float* wh_fw = (const float*)d_in[10];
  const float* bi_fw = (const float*)d_in[11];
  const float* bh_fw = (const float*)d_in[12];
  const float* wi_bw = (const float*)d_in[13];
  const float* wh_bw = (const float*)d_in[14];
  const float* bi_bw = (const float*)d_in[15];
  const float* bh_bw = (const float*)d_in[16];
  const float* e1w   = (const float*)d_in[17];
  const float* e1b   = (const float*)d_in[18];
  const float* e2w   = (const float*)d_in[19];
  const float* e2b   = (const float*)d_in[20];
  const float* e3w   = (const float*)d_in[21];
  const float* e3b   = (const float*)d_in[22];

  float* xt   = (float*)d_ws;   // [SL][48][NB] fp32 = 63 MB
  float* outp = (float*)d_out;

  msg_pass_kernel<<<(NB * SL) / 256, 256, 0, stream>>>(
      nf, pos, att, msg_w, msg_b, gw_ih, gw_hh, gb_ih, gb_hh, xt);

  lstm_head_kernel<<<NB / 64, 128, 0, stream>>>(
      xt, wi_fw, wh_fw, bi_fw, bh_fw, wi_bw, wh_bw, bi_bw, bh_bw,
      e1w, e1b, e2w, e2b, e3w, e3b, outp);
}

// Round 3
// 771.645 us; speedup vs baseline: 1.8143x; 1.8143x over previous
//
#include <hip/hip_runtime.h>
#include <cstddef>

#define NB 65536
#define SL 5

__device__ __forceinline__ float sigm(float x)   { return 1.0f / (1.0f + __expf(-x)); }
__device__ __forceinline__ float tanh_f(float x) { return 2.0f / (1.0f + __expf(-2.0f * x)) - 1.0f; }

// ---------------------------------------------------------------------------
// Phase A: thread = (b, s, node). Only m_all is exchanged between the 4 node
// threads (12KB LDS); GRU weights are wave-uniform s_loads; ~60 VGPRs.
// Writes x transposed as xt[s][feat=d*4+node][b] for coalesced phase-B reads.
// ---------------------------------------------------------------------------
__global__ __launch_bounds__(256) void msg_pass_kernel(
    const float* __restrict__ nf, const float* __restrict__ pos,
    const float* __restrict__ att,
    const float* __restrict__ msg_w, const float* __restrict__ msg_b,
    const float* __restrict__ gw_ih, const float* __restrict__ gw_hh,
    const float* __restrict__ gb_ih, const float* __restrict__ gb_hh,
    float* __restrict__ xt)
{
  __shared__ float ma_lds[12][256];
  const int tid  = threadIdx.x;
  const int t    = blockIdx.x * 256 + tid;
  const int node = t & 3;
  const int rem  = t >> 2;            // = s*NB + b
  const int s    = rem >> 16;         // NB = 65536
  const int b    = rem & (NB - 1);
  const size_t ibase = ((size_t)(b * SL + s) * 4 + node) * 6;

  // h init = concat(nodes_feature, pos) for own node
  float h[12];
  {
    const float2* n2 = (const float2*)(nf  + ibase);
    const float2* p2 = (const float2*)(pos + ibase);
#pragma unroll
    for (int q = 0; q < 3; q++) {
      float2 v = n2[q]; h[q*2]   = v.x; h[q*2+1]   = v.y;
      float2 u = p2[q]; h[6+q*2] = u.x; h[6+q*2+1] = u.y;
    }
  }
  float ta[4];
  {
    float4 v = *(const float4*)(att + ((size_t)(b * SL + s) * 4 + node) * 4);
    ta[0] = v.x; ta[1] = v.y; ta[2] = v.z; ta[3] = v.w;
  }

#pragma unroll 1
  for (int pass = 0; pass < 2; ++pass) {
    if (pass) __syncthreads();        // protect ma_lds from overwrite
    // m_all for own node
#pragma unroll
    for (int j = 0; j < 12; j++) {
      float a = msg_b[j];
#pragma unroll
      for (int i = 0; i < 12; i++) a = __builtin_fmaf(msg_w[j*12+i], h[i], a);
      ma_lds[j][tid] = a;
    }
    __syncthreads();
    const int base4 = tid & ~3;
    float mv[12];
#pragma unroll
    for (int j = 0; j < 12; j++) {
      mv[j] = ta[0]*ma_lds[j][base4]   + ta[1]*ma_lds[j][base4+1]
            + ta[2]*ma_lds[j][base4+2] + ta[3]*ma_lds[j][base4+3];
    }
    // GRU (gates r, z, n) for own node's 12 units
    float hn[12];
#pragma unroll
    for (int j = 0; j < 12; j++) {
      float ar  = gb_ih[j]    + gb_hh[j];
      float az  = gb_ih[12+j] + gb_hh[12+j];
      float ani = gb_ih[24+j];
      float anh = gb_hh[24+j];
#pragma unroll
      for (int i = 0; i < 12; i++) {
        const float mvi = mv[i], hi = h[i];
        ar  = __builtin_fmaf(gw_ih[j*12+i],      mvi, ar);
        ar  = __builtin_fmaf(gw_hh[j*12+i],      hi,  ar);
        az  = __builtin_fmaf(gw_ih[(12+j)*12+i], mvi, az);
        az  = __builtin_fmaf(gw_hh[(12+j)*12+i], hi,  az);
        ani = __builtin_fmaf(gw_ih[(24+j)*12+i], mvi, ani);
        anh = __builtin_fmaf(gw_hh[(24+j)*12+i], hi,  anh);
      }
      const float r = sigm(ar), z = sigm(az);
      const float g = tanh_f(ani + r * anh);
      hn[j] = (1.0f - z) * g + z * h[j];
    }
#pragma unroll
    for (int j = 0; j < 12; j++) h[j] = hn[j];
  }

#pragma unroll
  for (int d = 0; d < 12; d++)
    xt[(size_t)(s * 48 + d * 4 + node) * NB + b] = h[d];
}

// ---------------------------------------------------------------------------
// Phase B+C: biLSTM + MLP head. Block = 64 batches x 8 waves.
// Wave w: dir = w&1, unit-group ug = w>>1 (12 units) -> wave-uniform weight
// rows (s_loads). h double-buffered in LDS (1 barrier/step); c in LDS
// (own-thread slots); xv/hv in registers. MLP folded in, rows split across
// waves, c_lds reused as scratch. LDS = 48+24 = 72KB -> 2 blocks/CU.
// ---------------------------------------------------------------------------
__global__ __launch_bounds__(512, 4) void lstm_head_kernel(
    const float* __restrict__ xt,
    const float* __restrict__ wi_fw, const float* __restrict__ wh_fw,
    const float* __restrict__ bi_fw, const float* __restrict__ bh_fw,
    const float* __restrict__ wi_bw, const float* __restrict__ wh_bw,
    const float* __restrict__ bi_bw, const float* __restrict__ bh_bw,
    const float* __restrict__ e1w, const float* __restrict__ e1b,
    const float* __restrict__ e2w, const float* __restrict__ e2b,
    const float* __restrict__ e3w, const float* __restrict__ e3b,
    float* __restrict__ out)
{
  __shared__ float h_lds[2][96][64];   // [phase][dir*48+unit][batch] 48KB
  __shared__ float c_lds[96][64];      // [dir*48+unit][batch]        24KB

  const int tid  = threadIdx.x;
  const int lane = tid & 63;
  const int w    = __builtin_amdgcn_readfirstlane(tid >> 6);  // wave id 0..7
  const int dir  = w & 1;
  const int ug   = w >> 1;             // unit group 0..3
  const int b    = blockIdx.x * 64 + lane;
  const int urow = dir * 48 + ug * 12; // base row in [96]

  const float* __restrict__ wi = dir ? wi_bw : wi_fw;
  const float* __restrict__ wh = dir ? wh_bw : wh_fw;
  const float* __restrict__ bi = dir ? bi_bw : bi_fw;
  const float* __restrict__ bh = dir ? bh_bw : bh_fw;

#pragma unroll
  for (int j = 0; j < 12; j++) { h_lds[0][urow + j][lane] = 0.0f; c_lds[urow + j][lane] = 0.0f; }
  __syncthreads();

#pragma unroll 1
  for (int st = 0; st < 5; ++st) {
    const int p = st & 1;
    const int s = dir ? (4 - st) : st;
    float xv[48];
#pragma unroll
    for (int k = 0; k < 48; k++) xv[k] = xt[(size_t)(s * 48 + k) * NB + b];
    float hv[48];
#pragma unroll
    for (int k = 0; k < 48; k++) hv[k] = h_lds[p][dir * 48 + k][lane];

#pragma unroll 2
    for (int j = 0; j < 12; j++) {
      const int row = ug * 12 + j;
      float gi = bi[row]       + bh[row];
      float gf = bi[48 + row]  + bh[48 + row];
      float gg = bi[96 + row]  + bh[96 + row];
      float go = bi[144 + row] + bh[144 + row];
      const float* __restrict__ wij = wi + row * 48;
      const float* __restrict__ whj = wh + row * 48;
#pragma unroll
      for (int k = 0; k < 48; k++) {
        const float xk = xv[k];
        const float hk = hv[k];
        gi = __builtin_fmaf(wij[k],        xk, gi);
        gi = __builtin_fmaf(whj[k],        hk, gi);
        gf = __builtin_fmaf(wij[2304 + k], xk, gf);
        gf = __builtin_fmaf(whj[2304 + k], hk, gf);
        gg = __builtin_fmaf(wij[4608 + k], xk, gg);
        gg = __builtin_fmaf(whj[4608 + k], hk, gg);
        go = __builtin_fmaf(wij[6912 + k], xk, go);
        go = __builtin_fmaf(whj[6912 + k], hk, go);
      }
      const float cold = c_lds[urow + j][lane];
      const float c = sigm(gf) * cold + sigm(gi) * tanh_f(gg);
      c_lds[urow + j][lane] = c;
      h_lds[1 - p][urow + j][lane] = sigm(go) * tanh_f(c);
    }
    __syncthreads();
  }
  // final h (both dirs) sits in h_lds[1]: rows 0..47 = fw, 48..95 = bw = hcat

  // ---- MLP head, rows split across the 8 waves; c_lds reused as scratch ----
  float hcat[96];
#pragma unroll
  for (int k = 0; k < 96; k++) hcat[k] = h_lds[1][k][lane];
#pragma unroll
  for (int r = 0; r < 6; r++) {        // e1: 48 rows = 8 waves x 6
    const int rr = w * 6 + r;
    float a = e1b[rr];
#pragma unroll
    for (int k = 0; k < 96; k++) a = __builtin_fmaf(e1w[rr * 96 + k], hcat[k], a);
    c_lds[rr][lane] = a > 0.0f ? a : 0.0f;
  }
  __syncthreads();

  float e1v[48];
#pragma unroll
  for (int k = 0; k < 48; k++) e1v[k] = c_lds[k][lane];
  const int e2base = (w < 4) ? w * 5 : 20 + (w - 4) * 4;   // 36 rows: 5,5,5,5,4,4,4,4
  const int e2cnt  = (w < 4) ? 5 : 4;
#pragma unroll
  for (int r = 0; r < 5; r++) {
    if (r < e2cnt) {
      const int rr = e2base + r;
      float a = e2b[rr];
#pragma unroll
      for (int k = 0; k < 48; k++) a = __builtin_fmaf(e2w[rr * 48 + k], e1v[k], a);
      c_lds[48 + rr][lane] = a > 0.0f ? a : 0.0f;
    }
  }
  __syncthreads();

  if (w < 6) {                          // e3: 6 rows, one per wave
    float e2v[36];
#pragma unroll
    for (int k = 0; k < 36; k++) e2v[k] = c_lds[48 + k][lane];
    float a = e3b[w];
#pragma unroll
    for (int k = 0; k < 36; k++) a = __builtin_fmaf(e3w[w * 36 + k], e2v[k], a);
    out[(size_t)b * 6 + w] = a;
  }
}

extern "C" void kernel_launch(void* const* d_in, const int* in_sizes, int n_in,
                              void* d_out, int out_size, void* d_ws, size_t ws_size,
                              hipStream_t stream)
{
  const float* nf    = (const float*)d_in[0];
  const float* pos   = (const float*)d_in[1];
  const float* att   = (const float*)d_in[2];
  const float* msg_w = (const float*)d_in[3];
  const float* msg_b = (const float*)d_in[4];
  const float* gw_ih = (const float*)d_in[5];
  const float* gw_hh = (const float*)d_in[6];
  const float* gb_ih = (const float*)d_in[7];
  const float* gb_hh = (const float*)d_in[8];
  const float* wi_fw = (const float*)d_in[9];
  const float* wh_fw = (const float*)d_in[10];
  const float* bi_fw = (const float*)d_in[11];
  const float* bh_fw = (const float*)d_in[12];
  const float* wi_bw = (const float*)d_in[13];
  const float* wh_bw = (const float*)d_in[14];
  const float* bi_bw = (const float*)d_in[15];
  const float* bh_bw = (const float*)d_in[16];
  const float* e1w   = (const float*)d_in[17];
  const float* e1b   = (const float*)d_in[18];
  const float* e2w   = (const float*)d_in[19];
  const float* e2b   = (const float*)d_in[20];
  const float* e3w   = (const float*)d_in[21];
  const float* e3b   = (const float*)d_in[22];

  float* xt   = (float*)d_ws;   // [SL][48][NB] fp32 = 63 MB
  float* outp = (float*)d_out;

  msg_pass_kernel<<<(NB * SL * 4) / 256, 256, 0, stream>>>(
      nf, pos, att, msg_w, msg_b, gw_ih, gw_hh, gb_ih, gb_hh, xt);

  lstm_head_kernel<<<NB / 64, 512, 0, stream>>>(
      xt, wi_fw, wh_fw, bi_fw, bh_fw, wi_bw, wh_bw, bi_bw, bh_bw,
      e1w, e1b, e2w, e2b, e3w, e3b, outp);
}

// Round 4
// 728.747 us; speedup vs baseline: 1.9211x; 1.0589x over previous
//
#include <hip/hip_runtime.h>
#include <cstddef>

#define NB 65536
#define SL 5

__device__ __forceinline__ float sigm(float x)   { return 1.0f / (1.0f + __expf(-x)); }
__device__ __forceinline__ float tanh_f(float x) { return 2.0f / (1.0f + __expf(-2.0f * x)) - 1.0f; }

// ---------------------------------------------------------------------------
// Phase A: thread = (b, s, node). Only m_all is exchanged between the 4 node
// threads (12KB LDS); GRU weights are wave-uniform s_loads.
// Writes x transposed as xt[s][feat=d*4+node][b] for coalesced phase-B reads.
// (unchanged from round 3 — single-variable experiment on the LSTM kernel)
// ---------------------------------------------------------------------------
__global__ __launch_bounds__(256) void msg_pass_kernel(
    const float* __restrict__ nf, const float* __restrict__ pos,
    const float* __restrict__ att,
    const float* __restrict__ msg_w, const float* __restrict__ msg_b,
    const float* __restrict__ gw_ih, const float* __restrict__ gw_hh,
    const float* __restrict__ gb_ih, const float* __restrict__ gb_hh,
    float* __restrict__ xt)
{
  __shared__ float ma_lds[12][256];
  const int tid  = threadIdx.x;
  const int t    = blockIdx.x * 256 + tid;
  const int node = t & 3;
  const int rem  = t >> 2;            // = s*NB + b
  const int s    = rem >> 16;         // NB = 65536
  const int b    = rem & (NB - 1);
  const size_t ibase = ((size_t)(b * SL + s) * 4 + node) * 6;

  float h[12];
  {
    const float2* n2 = (const float2*)(nf  + ibase);
    const float2* p2 = (const float2*)(pos + ibase);
#pragma unroll
    for (int q = 0; q < 3; q++) {
      float2 v = n2[q]; h[q*2]   = v.x; h[q*2+1]   = v.y;
      float2 u = p2[q]; h[6+q*2] = u.x; h[6+q*2+1] = u.y;
    }
  }
  float ta[4];
  {
    float4 v = *(const float4*)(att + ((size_t)(b * SL + s) * 4 + node) * 4);
    ta[0] = v.x; ta[1] = v.y; ta[2] = v.z; ta[3] = v.w;
  }

#pragma unroll 1
  for (int pass = 0; pass < 2; ++pass) {
    if (pass) __syncthreads();
#pragma unroll
    for (int j = 0; j < 12; j++) {
      float a = msg_b[j];
#pragma unroll
      for (int i = 0; i < 12; i++) a = __builtin_fmaf(msg_w[j*12+i], h[i], a);
      ma_lds[j][tid] = a;
    }
    __syncthreads();
    const int base4 = tid & ~3;
    float mv[12];
#pragma unroll
    for (int j = 0; j < 12; j++) {
      mv[j] = ta[0]*ma_lds[j][base4]   + ta[1]*ma_lds[j][base4+1]
            + ta[2]*ma_lds[j][base4+2] + ta[3]*ma_lds[j][base4+3];
    }
    float hn[12];
#pragma unroll
    for (int j = 0; j < 12; j++) {
      float ar  = gb_ih[j]    + gb_hh[j];
      float az  = gb_ih[12+j] + gb_hh[12+j];
      float ani = gb_ih[24+j];
      float anh = gb_hh[24+j];
#pragma unroll
      for (int i = 0; i < 12; i++) {
        const float mvi = mv[i], hi = h[i];
        ar  = __builtin_fmaf(gw_ih[j*12+i],      mvi, ar);
        ar  = __builtin_fmaf(gw_hh[j*12+i],      hi,  ar);
        az  = __builtin_fmaf(gw_ih[(12+j)*12+i], mvi, az);
        az  = __builtin_fmaf(gw_hh[(12+j)*12+i], hi,  az);
        ani = __builtin_fmaf(gw_ih[(24+j)*12+i], mvi, ani);
        anh = __builtin_fmaf(gw_hh[(24+j)*12+i], hi,  anh);
      }
      const float r = sigm(ar), z = sigm(az);
      const float g = tanh_f(ani + r * anh);
      hn[j] = (1.0f - z) * g + z * h[j];
    }
#pragma unroll
    for (int j = 0; j < 12; j++) h[j] = hn[j];
  }

#pragma unroll
  for (int d = 0; d < 12; d++)
    xt[(size_t)(s * 48 + d * 4 + node) * NB + b] = h[d];
}

// ---------------------------------------------------------------------------
// Phase B+C: biLSTM + MLP head. Block = 64 batches x 8 waves.
// Wave w: dir = w&1, unit-group ug = w>>1 -> wave-uniform weight rows.
// Anti-spill structure: only xv[48] lives in registers; h is read straight
// from LDS inside the k-loop (lane-consecutive -> conflict-free; LGKM pipe
// runs under the FMA stream). Per-iteration memory clobber stops LICM from
// hoisting 48 LDS reads into registers (which caused the 319MB scratch spill
// at VGPR=64 in round 3). MLP reads activations LDS-direct for the same
// reason. No launch_bounds min-occupancy hint: LDS (72KB) caps at 2 blk/CU.
// ---------------------------------------------------------------------------
__global__ __launch_bounds__(512) void lstm_head_kernel(
    const float* __restrict__ xt,
    const float* __restrict__ wi_fw, const float* __restrict__ wh_fw,
    const float* __restrict__ bi_fw, const float* __restrict__ bh_fw,
    const float* __restrict__ wi_bw, const float* __restrict__ wh_bw,
    const float* __restrict__ bi_bw, const float* __restrict__ bh_bw,
    const float* __restrict__ e1w, const float* __restrict__ e1b,
    const float* __restrict__ e2w, const float* __restrict__ e2b,
    const float* __restrict__ e3w, const float* __restrict__ e3b,
    float* __restrict__ out)
{
  __shared__ float h_lds[2][96][64];   // [phase][dir*48+unit][batch] 48KB
  __shared__ float c_lds[96][64];      // [dir*48+unit][batch]        24KB

  const int tid  = threadIdx.x;
  const int lane = tid & 63;
  const int w    = __builtin_amdgcn_readfirstlane(tid >> 6);  // wave id 0..7
  const int dir  = w & 1;
  const int ug   = w >> 1;             // unit group 0..3
  const int b    = blockIdx.x * 64 + lane;
  const int urow = dir * 48 + ug * 12; // base row in [96]

  const float* __restrict__ wi = dir ? wi_bw : wi_fw;
  const float* __restrict__ wh = dir ? wh_bw : wh_fw;
  const float* __restrict__ bi = dir ? bi_bw : bi_fw;
  const float* __restrict__ bh = dir ? bh_bw : bh_fw;

#pragma unroll
  for (int j = 0; j < 12; j++) { h_lds[0][urow + j][lane] = 0.0f; c_lds[urow + j][lane] = 0.0f; }
  __syncthreads();

#pragma unroll 1
  for (int st = 0; st < 5; ++st) {
    const int p = st & 1;
    const int s = dir ? (4 - st) : st;
    float xv[48];                      // registers (SROA'd, static indices)
#pragma unroll
    for (int k = 0; k < 48; k++) xv[k] = xt[(size_t)(s * 48 + k) * NB + b];
    const float* __restrict__ hrow = &h_lds[p][dir * 48][0];  // stride 64/row

#pragma unroll 1
    for (int j = 0; j < 12; j++) {
      asm volatile("" ::: "memory");   // block LICM of the 48 h-reads
      const int row = ug * 12 + j;
      float gi = bi[row]       + bh[row];
      float gf = bi[48 + row]  + bh[48 + row];
      float gg = bi[96 + row]  + bh[96 + row];
      float go = bi[144 + row] + bh[144 + row];
      const float* __restrict__ wij = wi + row * 48;
      const float* __restrict__ whj = wh + row * 48;
#pragma unroll
      for (int k = 0; k < 48; k++) {
        const float xk = xv[k];
        const float hk = hrow[k * 64 + lane];   // LDS, conflict-free
        gi = __builtin_fmaf(wij[k],        xk, gi);
        gi = __builtin_fmaf(whj[k],        hk, gi);
        gf = __builtin_fmaf(wij[2304 + k], xk, gf);
        gf = __builtin_fmaf(whj[2304 + k], hk, gf);
        gg = __builtin_fmaf(wij[4608 + k], xk, gg);
        gg = __builtin_fmaf(whj[4608 + k], hk, gg);
        go = __builtin_fmaf(wij[6912 + k], xk, go);
        go = __builtin_fmaf(whj[6912 + k], hk, go);
      }
      const float cold = c_lds[urow + j][lane];
      const float c = sigm(gf) * cold + sigm(gi) * tanh_f(gg);
      c_lds[urow + j][lane] = c;
      h_lds[1 - p][urow + j][lane] = sigm(go) * tanh_f(c);
    }
    __syncthreads();
  }
  // final h (both dirs) is in h_lds[1]: rows 0..47 fw, 48..95 bw

  // ---- MLP head, rows split across 8 waves; activations read LDS-direct ----
#pragma unroll 1
  for (int r = 0; r < 6; r++) {        // e1: 48 rows = 8 waves x 6
    asm volatile("" ::: "memory");
    const int rr = w * 6 + r;
    float a = e1b[rr];
#pragma unroll
    for (int k = 0; k < 96; k++) a = __builtin_fmaf(e1w[rr * 96 + k], h_lds[1][k][lane], a);
    c_lds[rr][lane] = a > 0.0f ? a : 0.0f;
  }
  __syncthreads();

  const int e2base = (w < 4) ? w * 5 : 20 + (w - 4) * 4;   // 36 rows: 5,5,5,5,4,4,4,4
  const int e2cnt  = (w < 4) ? 5 : 4;
#pragma unroll 1
  for (int r = 0; r < 5; r++) {
    asm volatile("" ::: "memory");
    if (r < e2cnt) {
      const int rr = e2base + r;
      float a = e2b[rr];
#pragma unroll
      for (int k = 0; k < 48; k++) a = __builtin_fmaf(e2w[rr * 48 + k], c_lds[k][lane], a);
      c_lds[48 + rr][lane] = a > 0.0f ? a : 0.0f;
    }
  }
  __syncthreads();

  if (w < 6) {                          // e3: 6 rows, one per wave
    float a = e3b[w];
#pragma unroll
    for (int k = 0; k < 36; k++) a = __builtin_fmaf(e3w[w * 36 + k], c_lds[48 + k][lane], a);
    out[(size_t)b * 6 + w] = a;
  }
}

extern "C" void kernel_launch(void* const* d_in, const int* in_sizes, int n_in,
                              void* d_out, int out_size, void* d_ws, size_t ws_size,
                              hipStream_t stream)
{
  const float* nf    = (const float*)d_in[0];
  const float* pos   = (const float*)d_in[1];
  const float* att   = (const float*)d_in[2];
  const float* msg_w = (const float*)d_in[3];
  const float* msg_b = (const float*)d_in[4];
  const float* gw_ih = (const float*)d_in[5];
  const float* gw_hh = (const float*)d_in[6];
  const float* gb_ih = (const float*)d_in[7];
  const float* gb_hh = (const float*)d_in[8];
  const float* wi_fw = (const float*)d_in[9];
  const float* wh_fw = (const float*)d_in[10];
  const float* bi_fw = (const float*)d_in[11];
  const float* bh_fw = (const float*)d_in[12];
  const float* wi_bw = (const float*)d_in[13];
  const float* wh_bw = (const float*)d_in[14];
  const float* bi_bw = (const float*)d_in[15];
  const float* bh_bw = (const float*)d_in[16];
  const float* e1w   = (const float*)d_in[17];
  const float* e1b   = (const float*)d_in[18];
  const float* e2w   = (const float*)d_in[19];
  const float* e2b   = (const float*)d_in[20];
  const float* e3w   = (const float*)d_in[21];
  const float* e3b   = (const float*)d_in[22];

  float* xt   = (float*)d_ws;   // [SL][48][NB] fp32 = 63 MB
  float* outp = (float*)d_out;

  msg_pass_kernel<<<(NB * SL * 4) / 256, 256, 0, stream>>>(
      nf, pos, att, msg_w, msg_b, gw_ih, gw_hh, gb_ih, gb_hh, xt);

  lstm_head_kernel<<<NB / 64, 512, 0, stream>>>(
      xt, wi_fw, wh_fw, bi_fw, bh_fw, wi_bw, wh_bw, bi_bw, bh_bw,
      e1w, e1b, e2w, e2b, e3w, e3b, outp);
}